// Round 3
// baseline (383.023 us; speedup 1.0000x reference)
//
#include <hip/hip_runtime.h>

#define NFREQ 4

typedef float f4 __attribute__((ext_vector_type(4)));

// 7-point DFT coefficients: cos/sin(2*pi*m/7). Symmetry: cos(m)=cos(7-m),
// sin(m)=-sin(7-m) -> factored form below (verified vs C7[(k*n)%7] tables).
#define C1 0.62348980185873359f
#define C2 (-0.22252093395631440f)
#define C3 (-0.90096886790241915f)
#define S1 0.78183148246802980f
#define S2 0.97492791218182362f
#define S3 0.43388373911755812f

// One thread = 4 consecutive frames of one batch row.
// Frames f0..f0+3 need samples x[b*L + 2*f0 .. +11]: three 16B-ALIGNED float4
// loads (b*L*4 = 2,000,000*b bytes and 2*f0*4 = 32*t bytes, both %16==0).
// STORES: round-0 proven scalar guarded form (differential experiment —
// round 2's only unproven mechanism was unaligned 16B stores).
// PLANES layout (harness-verified round 0):
//   out[(b*4+k)*F + f] = re ; out[HALF + (b*4+k)*F + f] = im
__global__ __launch_bounds__(256) void stft4(
    const float* __restrict__ x, const float* __restrict__ w,
    float* __restrict__ out,
    long long L, long long F, long long HALF, long long in0, long long outn)
{
    const long long t = (long long)blockIdx.x * blockDim.x + threadIdx.x;
    const long long nG = (F + 3) >> 2;            // frame-groups of 4
    if (t >= nG) return;
    const long long b = blockIdx.y;

    // window reads are wave-uniform -> scalar-cached
    const float w0 = w[0], w1 = w[1], w2 = w[2], w3 = w[3], w4 = w[4], w5 = w[5];

    const long long f0 = t << 2;
    const long long xbase = b * L + 2 * f0;

    float s[12];
    if ((f0 + 3 < F) && (xbase + 12 <= in0)) {
        // fast path: 3 aligned 16B loads
        f4 va, vb, vc;
        __builtin_memcpy(&va, x + xbase,      16);
        __builtin_memcpy(&vb, x + xbase + 4,  16);
        __builtin_memcpy(&vc, x + xbase + 8,  16);
        s[0]=va.x; s[1]=va.y; s[2]=va.z;  s[3]=va.w;
        s[4]=vb.x; s[5]=vb.y; s[6]=vb.z;  s[7]=vb.w;
        s[8]=vc.x; s[9]=vc.y; s[10]=vc.z; s[11]=vc.w;
    } else {
        // tail/fallback: guarded scalar loads (unused slots zeroed)
#pragma unroll
        for (int i = 0; i < 12; ++i)
            s[i] = (xbase + i < in0) ? x[xbase + i] : 0.f;
    }

#pragma unroll
    for (int j = 0; j < 4; ++j) {                 // full unroll: s[] indices
        if (f0 + j >= F) break;                   // are all compile-time
        const float wx0 = s[2*j+0] * w0, wx1 = s[2*j+1] * w1;
        const float wx2 = s[2*j+2] * w2, wx3 = s[2*j+3] * w3;
        const float wx4 = s[2*j+4] * w4, wx5 = s[2*j+5] * w5;
        const float p2 = wx2 + wx5, p3 = wx3 + wx4;    // cos-symmetric pairs
        const float m2 = wx2 - wx5, m3 = wx3 - wx4;    // sin-antisymmetric

        const float re0 = wx0 + wx1 + p2 + p3;         // k=0 (im == 0)
        const float re1 = fmaf(C1, wx1, fmaf(C2, p2, fmaf(C3, p3, wx0)));
        const float re2 = fmaf(C2, wx1, fmaf(C3, p2, fmaf(C1, p3, wx0)));
        const float re3 = fmaf(C3, wx1, fmaf(C1, p2, fmaf(C2, p3, wx0)));
        const float im1 = -fmaf(S1, wx1, fmaf(S2, m2,  S3 * m3));
        const float im2 = fmaf(-S2, wx1, fmaf(S3, m2,  S1 * m3));
        const float im3 = fmaf(-S3, wx1, fmaf(S1, m2, -S2 * m3));

        const long long f = f0 + j;
        const long long q0 = (b * NFREQ + 0) * F + f;
        const long long q1 = q0 + F;
        const long long q2 = q1 + F;
        const long long q3 = q2 + F;
        // round-0 proven store form: scalar, per-store guard
        if (q0 < outn)        out[q0] = re0;
        if (HALF + q0 < outn) out[HALF + q0] = 0.f;
        if (q1 < outn)        out[q1] = re1;
        if (HALF + q1 < outn) out[HALF + q1] = im1;
        if (q2 < outn)        out[q2] = re2;
        if (HALF + q2 < outn) out[HALF + q2] = im2;
        if (q3 < outn)        out[q3] = re3;
        if (HALF + q3 < outn) out[HALF + q3] = im3;
    }
}

extern "C" void kernel_launch(void* const* d_in, const int* in_sizes, int n_in,
                              void* d_out, int out_size, void* d_ws, size_t ws_size,
                              hipStream_t stream) {
    const float* x = (const float*)d_in[0];
    const float* w = (const float*)d_in[1];
    float* out = (float*)d_out;

    const long long B = 64;                          // fixed by the reference
    const long long L = (long long)in_sizes[0] / B;  // 500000
    const long long F = 1 + (L - 7) / 2;             // 249997
    const long long HALF = B * NFREQ * F;            // re-plane size
    const long long nG = (F + 3) / 4;                // 62500 frame-groups

    dim3 block(256);
    dim3 grid((unsigned)((nG + 255) / 256), (unsigned)B);
    stft4<<<grid, block, 0, stream>>>(x, w, out, L, F, HALF,
                                      (long long)in_sizes[0],
                                      (long long)out_size);
}

// Round 4
// 381.839 us; speedup vs baseline: 1.0031x; 1.0031x over previous
//
#include <hip/hip_runtime.h>

typedef float f4 __attribute__((ext_vector_type(4)));

// 7-point DFT coefficients: cos/sin(2*pi*m/7), factored via
// cos(m)=cos(7-m), sin(m)=-sin(7-m). Formulas identical to round-3 PASS.
#define C1f 0.62348980185873359f
#define C2f (-0.22252093395631440f)
#define C3f (-0.90096886790241915f)
#define S1f 0.78183148246802980f
#define S2f 0.97492791218182362f
#define S3f 0.43388373911755812f

// Flat-output ownership: out has 512*F dwords (512 planes of F frames,
// plane P = part*256 + b*4 + k; planes contiguous). Thread owns ONE
// 16B-ALIGNED quad of dwords [4q, 4q+4). Quad q belongs to the plane
// containing its first dword: q in [ceil(pF/4), ceil((p+1)F/4)).
// Fast path: all 4 dwords in-plane -> 4 aligned 16B input loads,
// compute plane-k value for 4 frames, ONE aligned 16B store.
// Straddle (last quad of a plane, <=512 threads) + any guard failure:
// per-dword scalar path.
__global__ __launch_bounds__(256) void stft_flat(
    const float* __restrict__ x, const float* __restrict__ w,
    float* __restrict__ out, int L, int F, int inN, int outN)
{
    const int bx = (int)blockIdx.x;
    const int p  = bx & 511;                 // plane id (block-uniform, fastest grid dim)
    const int i  = (bx >> 9) * 256 + (int)threadIdx.x;

    const int pF  = p * F;                   // <= 511*249997 < 2^31
    const int qb  = (pF + 3) >> 2;           // first quad owned by plane p
    const int nQp = (((p + 1) * F + 3) >> 2) - qb;
    if (i >= nQp) return;

    const int k    = p & 3;
    const int b    = (p >> 2) & 63;
    const int part = p >> 8;                 // 0 = re, 1 = im

    const int d0 = (qb + i) << 2;            // aligned output dword (16B)
    const int f0 = d0 - pF;                  // first frame, in [0, F)

    const float w0=w[0], w1=w[1], w2=w[2], w3=w[3], w4=w[4], w5=w[5];

    const int xo = b * L + 2 * f0;           // first needed sample (even)
    const int xd = xo & ~3;                  // 16B-aligned load base

    if ((f0 + 3 < F) && (xd + 16 <= inN) && (d0 + 4 <= outN) && ((xo & 1) == 0)) {
        // ---- fast path: 4 aligned 16B loads cover samples xo..xo+11 ----
        f4 A, B2, C2v, D2;
        __builtin_memcpy(&A,   x + xd,      16);
        __builtin_memcpy(&B2,  x + xd + 4,  16);
        __builtin_memcpy(&C2v, x + xd + 8,  16);
        __builtin_memcpy(&D2,  x + xd + 12, 16);
        float s0=A.x,  s1=A.y,  s2=A.z,  s3=A.w,
              s4=B2.x, s5=B2.y, s6=B2.z, s7=B2.w,
              s8=C2v.x,s9=C2v.y,s10=C2v.z,s11=C2v.w,
              s12=D2.x,s13=D2.y;
        if (xo != xd) {                      // off==2 (block-uniform shift)
            s0=s2; s1=s3; s2=s4; s3=s5; s4=s6;  s5=s7;
            s6=s8; s7=s9; s8=s10; s9=s11; s10=s12; s11=s13;
        }

        f4 v;
        if (part == 0) {
            float ca, cb, cc;                // re coeffs, uniform select on k
            if      (k == 0) { ca=1.f; cb=1.f; cc=1.f; }
            else if (k == 1) { ca=C1f; cb=C2f; cc=C3f; }
            else if (k == 2) { ca=C2f; cb=C3f; cc=C1f; }
            else             { ca=C3f; cb=C1f; cc=C2f; }
#define REJ(a0,a1,a2,a3,a4,a5) ({ \
            const float wx0=(a0)*w0, wx1=(a1)*w1; \
            const float pp2=(a2)*w2 + (a5)*w5; \
            const float pp3=(a3)*w3 + (a4)*w4; \
            fmaf(ca, wx1, fmaf(cb, pp2, fmaf(cc, pp3, wx0))); })
            v.x = REJ(s0,s1,s2,s3,s4,s5);
            v.y = REJ(s2,s3,s4,s5,s6,s7);
            v.z = REJ(s4,s5,s6,s7,s8,s9);
            v.w = REJ(s6,s7,s8,s9,s10,s11);
#undef REJ
        } else {
            float sa, sb, sc;                // im coeffs, uniform select on k
            if      (k == 0) { sa=0.f; sb=0.f;   sc=0.f;  }
            else if (k == 1) { sa=S1f; sb=S2f;   sc=S3f;  }
            else if (k == 2) { sa=S2f; sb=-S3f;  sc=-S1f; }
            else             { sa=S3f; sb=-S1f;  sc=S2f;  }
#define IMJ(a1,a2,a3,a4,a5) ({ \
            const float wx1=(a1)*w1; \
            const float mm2=(a2)*w2 - (a5)*w5; \
            const float mm3=(a3)*w3 - (a4)*w4; \
            -fmaf(sa, wx1, fmaf(sb, mm2, sc * mm3)); })
            v.x = IMJ(s1,s2,s3,s4,s5);
            v.y = IMJ(s3,s4,s5,s6,s7);
            v.z = IMJ(s5,s6,s7,s8,s9);
            v.w = IMJ(s7,s8,s9,s10,s11);
#undef IMJ
        }
        __builtin_memcpy(out + d0, &v, 16);  // 16B-ALIGNED vector store
        return;
    }

    // ---- slow path: plane-straddling quad or guard failure ----
    const int OUTt = F << 9;                 // 512*F
    for (int j = 0; j < 4; ++j) {
        const int d = d0 + j;
        if (d >= outN || d >= OUTt) return;
        int pd = p, fd = d - pF;
        if (fd >= F) { pd = p + 1; fd -= F; }    // d < 512F -> pd <= 511
        const int kd = pd & 3, bd = (pd >> 2) & 63, partd = pd >> 8;
        const int base = bd * L + 2 * fd;
        const float sx0 = (base + 0 < inN) ? x[base + 0] : 0.f;
        const float sx1 = (base + 1 < inN) ? x[base + 1] : 0.f;
        const float sx2 = (base + 2 < inN) ? x[base + 2] : 0.f;
        const float sx3 = (base + 3 < inN) ? x[base + 3] : 0.f;
        const float sx4 = (base + 4 < inN) ? x[base + 4] : 0.f;
        const float sx5 = (base + 5 < inN) ? x[base + 5] : 0.f;
        const float wx0=sx0*w0, wx1=sx1*w1, wx2=sx2*w2;
        const float wx3=sx3*w3, wx4=sx4*w4, wx5=sx5*w5;
        float val;
        if (partd == 0) {
            const float p2 = wx2 + wx5, p3 = wx3 + wx4;
            float ca, cb, cc;
            if      (kd == 0) { ca=1.f; cb=1.f; cc=1.f; }
            else if (kd == 1) { ca=C1f; cb=C2f; cc=C3f; }
            else if (kd == 2) { ca=C2f; cb=C3f; cc=C1f; }
            else              { ca=C3f; cb=C1f; cc=C2f; }
            val = fmaf(ca, wx1, fmaf(cb, p2, fmaf(cc, p3, wx0)));
        } else {
            const float m2 = wx2 - wx5, m3 = wx3 - wx4;
            float sa, sb, sc;
            if      (kd == 0) { sa=0.f; sb=0.f;   sc=0.f;  }
            else if (kd == 1) { sa=S1f; sb=S2f;   sc=S3f;  }
            else if (kd == 2) { sa=S2f; sb=-S3f;  sc=-S1f; }
            else              { sa=S3f; sb=-S1f;  sc=S2f;  }
            val = -fmaf(sa, wx1, fmaf(sb, m2, sc * m3));
        }
        out[d] = val;
    }
}

extern "C" void kernel_launch(void* const* d_in, const int* in_sizes, int n_in,
                              void* d_out, int out_size, void* d_ws, size_t ws_size,
                              hipStream_t stream) {
    const float* x = (const float*)d_in[0];
    const float* w = (const float*)d_in[1];
    float* out = (float*)d_out;

    const long long B = 64;                          // fixed by the reference
    const long long L = (long long)in_sizes[0] / B;  // 500000
    const long long F = 1 + (L - 7) / 2;             // 249997

    const int maxNQ = (int)((F + 3) / 4 + 1);        // >= any plane's quad count
    const int nib   = (maxNQ + 255) / 256;           // i-blocks per plane (245)

    dim3 block(256);
    dim3 grid((unsigned)(nib * 512));                // plane id fastest (bx & 511)
    stft_flat<<<grid, block, 0, stream>>>(x, w, out,
                                          (int)L, (int)F,
                                          in_sizes[0], out_size);
}